// Round 1
// baseline (179.573 us; speedup 1.0000x reference)
//
#include <hip/hip_runtime.h>

// CIN forward: B=2048, F=32, DIM=64, layers (128,128)
// out[b, 0:64]   = sum_d relu(W0 @ z0 + b0)[64:128, d]
// out[b, 64:192] = sum_d relu(W1 @ z1 + b1)[0:128, d]
// z0[h*32+m, d] = x[h,d]*x[m,d]   (h,m in [0,32))
// z1[h*32+m, d] = h1[h,d]*x[m,d]  (h in [0,64), m in [0,32)), h1 = layer0 rows 0..63
//
// R3: 32x32x16 f16 MFMA (higher matrix rate, 4x fewer MFMA issue slots,
// 1 A-load per 32 output rows), plus parallel/coalesced convert_w
// (old one ran 192 blocks, latency-bound, suspected ~60us straggler).
//
// Fragment mapping (gfx950, v_mfma_f32_32x32x16_f16):
//   A (32x16): row = lane&31, k = (lane>>5)*8 + j   (8 f16/lane)
//   B (16x32): col = lane&31, k = (lane>>5)*8 + j
//   C/D:       col = lane&31, row = (reg&3) + 8*(reg>>2) + 4*(lane>>5)

#define BATCH 2048
#define FSZ   32
#define DIM   64
#define K0    1024
#define K1    2048
#define OUTC  192

#define W0_ELEMS (128 * K0)            // 131072 f16
#define W1_ELEMS (128 * K1)            // 262144 f16
#define TOT_ELEMS (W0_ELEMS + W1_ELEMS)
#define CVT_THREADS (TOT_ELEMS / 4)    // 98304 -> 384 blocks

typedef _Float16 v8h  __attribute__((ext_vector_type(8)));
typedef float    v16f __attribute__((ext_vector_type(16)));

#define XT_PITCH 40   // xT[d][m]: 80B rows, 16B-aligned v8h loads
#define XD_PITCH 66   // xD[m][d]: scalar broadcast reads, conflict-free
#define HD_PITCH 66   // h1D[h][d]

// Swizzle W into 32x32x16 A-fragment order:
//   frag f = ks*256 + ob*64 + lane
//   wsw[f*8 + j] = W[ob*32 + (lane&31)][ks*16 + (lane>>5)*8 + j]
// One thread per 4 output f16: 16B contiguous read, 8B contiguous write.
__global__ void convert_w_kernel(const float* __restrict__ W0,
                                 const float* __restrict__ W1,
                                 _Float16* __restrict__ wsw) {
    int t = blockIdx.x * blockDim.x + threadIdx.x;
    if (t >= CVT_THREADS) return;
    int e = t * 4;
    const float* src;
    if (e < W0_ELEMS) {
        int f = e >> 3, j0 = e & 7;
        int ks = f >> 8, ob = (f >> 6) & 3, lane = f & 63;
        src = W0 + (size_t)(ob * 32 + (lane & 31)) * K0
                 + ks * 16 + (lane >> 5) * 8 + j0;
    } else {
        int u = e - W0_ELEMS;
        int f = u >> 3, j0 = u & 7;
        int ks = f >> 8, ob = (f >> 6) & 3, lane = f & 63;
        src = W1 + (size_t)(ob * 32 + (lane & 31)) * K1
                 + ks * 16 + (lane >> 5) * 8 + j0;
    }
    float4 v = *(const float4*)src;
    _Float16* dst = wsw + e;
    dst[0] = (_Float16)v.x;
    dst[1] = (_Float16)v.y;
    dst[2] = (_Float16)v.z;
    dst[3] = (_Float16)v.w;
}

__global__ __launch_bounds__(256, 4) void cin_kernel(
    const float* __restrict__ X,      // (B, 32, 64) fp32
    const float* __restrict__ b0,     // (128,)
    const float* __restrict__ b1,     // (128,)
    const _Float16* __restrict__ Wsw, // swizzled W0 then W1 (f16)
    float* __restrict__ out)          // (B, 192) fp32
{
    __shared__ _Float16 xT[DIM * XT_PITCH];     // xT[d][m] = x[m][d]
    __shared__ _Float16 xD[FSZ * XD_PITCH];     // xD[m][d] = x[m][d]
    __shared__ _Float16 h1D[64 * HD_PITCH];     // h1D[h][d]

    const int b    = blockIdx.x;
    const int tid  = threadIdx.x;
    const int wave = tid >> 6;        // = o-block (32 rows each)
    const int lane = tid & 63;
    const int half = lane >> 5;
    const int d0   = lane & 31;

    // ---- stage x -> LDS (both layouts, f16) ----
    const float* xb = X + (size_t)b * (FSZ * DIM);
    #pragma unroll
    for (int i = tid; i < FSZ * DIM; i += 256) {
        int m = i >> 6, d = i & 63;
        _Float16 v = (_Float16)xb[i];
        xT[d * XT_PITCH + m] = v;
        xD[m * XD_PITCH + d] = v;
    }
    __syncthreads();

    // K-invariant x-vector parts of the B fragment:
    //   xh[db][p][j] = x[p*16 + half*8 + j][db*32 + d0]
    v8h xh[2][2];
    #pragma unroll
    for (int db = 0; db < 2; ++db)
        #pragma unroll
        for (int p = 0; p < 2; ++p)
            xh[db][p] = *(const v8h*)(&xT[(db * 32 + d0) * XT_PITCH + p * 16 + half * 8]);

    // ================= layer 0 =================
    v16f acc0 = (v16f)0.0f;   // d-block 0 (d 0..31)
    v16f acc1 = (v16f)0.0f;   // d-block 1 (d 32..63)

    {
        const _Float16* Wk = Wsw + (size_t)(wave * 64 + lane) * 8;
        #pragma unroll 4
        for (int ks = 0; ks < 64; ++ks) {          // K-step of 16; k = ks*16+half*8+j
            v8h a = *(const v8h*)(Wk + (size_t)ks * 2048);
            const int hr = ks >> 1;                // h index of this K-step
            _Float16 s0 = xD[hr * XD_PITCH + d0];
            _Float16 s1 = xD[hr * XD_PITCH + 32 + d0];
            v8h s08 = {s0, s0, s0, s0, s0, s0, s0, s0};
            v8h s18 = {s1, s1, s1, s1, s1, s1, s1, s1};
            v8h bf0 = s08 * xh[0][ks & 1];
            v8h bf1 = s18 * xh[1][ks & 1];
            acc0 = __builtin_amdgcn_mfma_f32_32x32x16_f16(a, bf0, acc0, 0, 0, 0);
            acc1 = __builtin_amdgcn_mfma_f32_32x32x16_f16(a, bf1, acc1, 0, 0, 0);
        }
    }

    // ---- epilogue 0: rows 0..63 -> h1D (LDS); rows 64..127 -> out[b, o-64] ----
    if (wave < 2) {
        #pragma unroll
        for (int reg = 0; reg < 16; ++reg) {
            const int o = wave * 32 + (reg & 3) + 8 * (reg >> 2) + 4 * half;
            const float bias = b0[o];
            float v0 = acc0[reg] + bias; v0 = v0 > 0.0f ? v0 : 0.0f;
            float v1 = acc1[reg] + bias; v1 = v1 > 0.0f ? v1 : 0.0f;
            h1D[o * HD_PITCH + d0]      = (_Float16)v0;
            h1D[o * HD_PITCH + 32 + d0] = (_Float16)v1;
        }
    } else {
        #pragma unroll
        for (int reg = 0; reg < 16; ++reg) {
            const int o = wave * 32 + (reg & 3) + 8 * (reg >> 2) + 4 * half;
            const float bias = b0[o];
            float v0 = acc0[reg] + bias; v0 = v0 > 0.0f ? v0 : 0.0f;
            float v1 = acc1[reg] + bias; v1 = v1 > 0.0f ? v1 : 0.0f;
            float s = v0 + v1;
            s += __shfl_xor(s, 1);
            s += __shfl_xor(s, 2);
            s += __shfl_xor(s, 4);
            s += __shfl_xor(s, 8);
            s += __shfl_xor(s, 16);
            if (d0 == 0) out[(size_t)b * OUTC + (o - 64)] = s;
        }
    }
    __syncthreads();

    // ================= layer 1 =================
    acc0 = (v16f)0.0f;
    acc1 = (v16f)0.0f;

    {
        const _Float16* Wk = Wsw + W0_ELEMS + (size_t)(wave * 64 + lane) * 8;
        #pragma unroll 4
        for (int ks = 0; ks < 128; ++ks) {
            v8h a = *(const v8h*)(Wk + (size_t)ks * 2048);
            const int hr = ks >> 1;                // h index in [0,64)
            _Float16 s0 = h1D[hr * HD_PITCH + d0];
            _Float16 s1 = h1D[hr * HD_PITCH + 32 + d0];
            v8h s08 = {s0, s0, s0, s0, s0, s0, s0, s0};
            v8h s18 = {s1, s1, s1, s1, s1, s1, s1, s1};
            v8h bf0 = s08 * xh[0][ks & 1];
            v8h bf1 = s18 * xh[1][ks & 1];
            acc0 = __builtin_amdgcn_mfma_f32_32x32x16_f16(a, bf0, acc0, 0, 0, 0);
            acc1 = __builtin_amdgcn_mfma_f32_32x32x16_f16(a, bf1, acc1, 0, 0, 0);
        }
    }

    // ---- epilogue 1: all 128 rows -> out[b, 64+o] ----
    #pragma unroll
    for (int reg = 0; reg < 16; ++reg) {
        const int o = wave * 32 + (reg & 3) + 8 * (reg >> 2) + 4 * half;
        const float bias = b1[o];
        float v0 = acc0[reg] + bias; v0 = v0 > 0.0f ? v0 : 0.0f;
        float v1 = acc1[reg] + bias; v1 = v1 > 0.0f ? v1 : 0.0f;
        float s = v0 + v1;
        s += __shfl_xor(s, 1);
        s += __shfl_xor(s, 2);
        s += __shfl_xor(s, 4);
        s += __shfl_xor(s, 8);
        s += __shfl_xor(s, 16);
        if (d0 == 0) out[(size_t)b * OUTC + 64 + o] = s;
    }
}

extern "C" void kernel_launch(void* const* d_in, const int* in_sizes, int n_in,
                              void* d_out, int out_size, void* d_ws, size_t ws_size,
                              hipStream_t stream) {
    const float* X  = (const float*)d_in[0];
    const float* W0 = (const float*)d_in[1];
    const float* b0 = (const float*)d_in[2];
    const float* W1 = (const float*)d_in[3];
    const float* b1 = (const float*)d_in[4];
    float* out = (float*)d_out;
    _Float16* wsw = (_Float16*)d_ws;  // needs 768 KB

    convert_w_kernel<<<(CVT_THREADS + 255) / 256, 256, 0, stream>>>(W0, W1, wsw);
    cin_kernel<<<BATCH, 256, 0, stream>>>(X, b0, b1, wsw, out);
}

// Round 2
// 150.149 us; speedup vs baseline: 1.1960x; 1.1960x over previous
//
#include <hip/hip_runtime.h>

// CIN forward: B=2048, F=32, DIM=64, layers (128,128)
// out[b, 0:64]   = sum_d relu(W0 @ z0 + b0)[64:128, d]
// out[b, 64:192] = sum_d relu(W1 @ z1 + b1)[0:128, d]
// z0[h*32+m, d] = x[h,d]*x[m,d]   (h,m in [0,32))
// z1[h*32+m, d] = h1[h,d]*x[m,d]  (h in [0,64), m in [0,32)), h1 = layer0 rows 0..63
//
// R4: back to 16x16x32 f16 MFMA (R3's 32x32 lost ILP: 2 dep chains, MfmaUtil
// 49->39). New wave mapping to cut redundant B-fragment VALU: block handles
// TWO batches; wave (p=wave&1, rh=wave>>1) owns 64 output rows (4 A-frags)
// x all 4 d-groups for batch p. Per K-step: 4 bfr (16 pk_mul) feed 16 MFMAs
// -> 1 pk_mul/MFMA (was 2). Per-batch W L2 traffic unchanged; 16 acc chains.
//
// A-frag swizzle (16x16x32): wsw[ks*4096 + s*512 + lane*8 + j]
//   = W[(s*16 + (lane&15))*K + ks*32 + (lane>>4)*8 + j]

#define BATCH 2048
#define FSZ   32
#define DIM   64
#define K0    1024
#define K1    2048
#define OUTC  192

#define W0_ELEMS (128 * K0)            // 131072 f16
#define W1_ELEMS (128 * K1)            // 262144 f16
#define TOT_ELEMS (W0_ELEMS + W1_ELEMS)
#define CVT_THREADS (TOT_ELEMS / 4)    // 98304 -> 384 blocks

typedef _Float16 v8h __attribute__((ext_vector_type(8)));
typedef float    v4f __attribute__((ext_vector_type(4)));

#define XT_PITCH 40   // xT[d][m]: 80B rows, 16B-aligned v8h loads
#define XD_PITCH 66   // xD[m][d]: scalar broadcast reads
#define HD_PITCH 66   // h1D[h][d]

// One thread per 4 output f16: coalesced 8B stores, aligned float4 reads.
// Decode of elem index e: j = e&7, lane = (e>>3)&63, s = (e>>9)&7, ks = e>>12.
__global__ void convert_w_kernel(const float* __restrict__ W0,
                                 const float* __restrict__ W1,
                                 _Float16* __restrict__ wsw) {
    int t = blockIdx.x * blockDim.x + threadIdx.x;
    if (t >= CVT_THREADS) return;
    int e = t * 4;
    const float* src;
    _Float16* dst;
    if (e < W0_ELEMS) {
        int j0 = e & 7, lane = (e >> 3) & 63, s = (e >> 9) & 7, ks = e >> 12;
        src = W0 + (size_t)(s * 16 + (lane & 15)) * K0
                 + ks * 32 + (lane >> 4) * 8 + j0;
        dst = wsw + e;
    } else {
        int u = e - W0_ELEMS;
        int j0 = u & 7, lane = (u >> 3) & 63, s = (u >> 9) & 7, ks = u >> 12;
        src = W1 + (size_t)(s * 16 + (lane & 15)) * K1
                 + ks * 32 + (lane >> 4) * 8 + j0;
        dst = wsw + W0_ELEMS + u;
    }
    float4 v = *(const float4*)src;
    dst[0] = (_Float16)v.x;
    dst[1] = (_Float16)v.y;
    dst[2] = (_Float16)v.z;
    dst[3] = (_Float16)v.w;
}

__global__ __launch_bounds__(256, 4) void cin_kernel(
    const float* __restrict__ X,      // (B, 32, 64) fp32
    const float* __restrict__ b0,     // (128,)
    const float* __restrict__ b1,     // (128,)
    const _Float16* __restrict__ Wsw, // swizzled W0 then W1 (f16)
    float* __restrict__ out)          // (B, 192) fp32
{
    __shared__ _Float16 xT[2][DIM * XT_PITCH];   // xT[p][d][m]
    __shared__ _Float16 xD[2][FSZ * XD_PITCH];   // xD[p][m][d]
    __shared__ _Float16 h1D[2][64 * HD_PITCH];   // h1D[p][h][d]

    const int b0i  = blockIdx.x * 2;
    const int tid  = threadIdx.x;
    const int wave = tid >> 6;
    const int lane = tid & 63;
    const int p    = wave & 1;        // batch member
    const int rh   = wave >> 1;       // row half (64 rows)
    const int quad = lane >> 4;
    const int col  = lane & 15;

    // ---- stage both batches' x -> LDS (both layouts, f16) ----
    #pragma unroll
    for (int i = tid; i < 2 * FSZ * DIM / 4; i += 256) {   // 1024 float4s
        int pp = i >> 9, r4 = i & 511;
        float4 v = *(const float4*)(X + (size_t)(b0i + pp) * (FSZ * DIM) + r4 * 4);
        int m = (r4 * 4) >> 6, d = (r4 * 4) & 63;
        _Float16 f0 = (_Float16)v.x, f1 = (_Float16)v.y,
                 f2 = (_Float16)v.z, f3 = (_Float16)v.w;
        xT[pp][(d + 0) * XT_PITCH + m] = f0;
        xT[pp][(d + 1) * XT_PITCH + m] = f1;
        xT[pp][(d + 2) * XT_PITCH + m] = f2;
        xT[pp][(d + 3) * XT_PITCH + m] = f3;
        xD[pp][m * XD_PITCH + d + 0] = f0;
        xD[pp][m * XD_PITCH + d + 1] = f1;
        xD[pp][m * XD_PITCH + d + 2] = f2;
        xD[pp][m * XD_PITCH + d + 3] = f3;
    }
    __syncthreads();

    // K-invariant x parts of B fragments: xv8[t][j] = x[quad*8+j][16t+col]
    v8h xv8[4];
    int dd[4];
    #pragma unroll
    for (int t = 0; t < 4; ++t) {
        dd[t] = 16 * t + col;
        xv8[t] = *(const v8h*)(&xT[p][dd[t] * XT_PITCH + quad * 8]);
    }

    // ================= layer 0 =================
    v4f acc[4][4];
    #pragma unroll
    for (int f = 0; f < 4; ++f)
        #pragma unroll
        for (int t = 0; t < 4; ++t) acc[f][t] = (v4f)0.0f;

    {
        const _Float16* Wk = Wsw + (size_t)(rh * 4) * 512 + (size_t)lane * 8;
        #pragma unroll 2
        for (int ks = 0; ks < 32; ++ks) {        // h = ks, m = quad*8+j
            v8h a0 = *(const v8h*)(Wk);
            v8h a1 = *(const v8h*)(Wk + 512);
            v8h a2 = *(const v8h*)(Wk + 1024);
            v8h a3 = *(const v8h*)(Wk + 1536);
            Wk += 4096;
            #pragma unroll
            for (int t = 0; t < 4; ++t) {
                _Float16 s = xD[p][ks * XD_PITCH + dd[t]];
                v8h s8 = {s, s, s, s, s, s, s, s};
                v8h bfr = s8 * xv8[t];
                acc[0][t] = __builtin_amdgcn_mfma_f32_16x16x32_f16(a0, bfr, acc[0][t], 0, 0, 0);
                acc[1][t] = __builtin_amdgcn_mfma_f32_16x16x32_f16(a1, bfr, acc[1][t], 0, 0, 0);
                acc[2][t] = __builtin_amdgcn_mfma_f32_16x16x32_f16(a2, bfr, acc[2][t], 0, 0, 0);
                acc[3][t] = __builtin_amdgcn_mfma_f32_16x16x32_f16(a3, bfr, acc[3][t], 0, 0, 0);
            }
        }
    }

    // ---- epilogue 0 ----
    // rh=0: rows 0..63 -> h1D[p]; rh=1: rows 64..127 -> out[b, o-64]
    if (rh == 0) {
        #pragma unroll
        for (int f = 0; f < 4; ++f) {
            #pragma unroll
            for (int reg = 0; reg < 4; ++reg) {
                const int o = f * 16 + quad * 4 + reg;
                const float bias = b0[o];
                #pragma unroll
                for (int t = 0; t < 4; ++t) {
                    float v = acc[f][t][reg] + bias;
                    v = v > 0.0f ? v : 0.0f;
                    h1D[p][o * HD_PITCH + dd[t]] = (_Float16)v;
                }
            }
        }
    } else {
        #pragma unroll
        for (int f = 0; f < 4; ++f) {
            #pragma unroll
            for (int reg = 0; reg < 4; ++reg) {
                const int o = 64 + f * 16 + quad * 4 + reg;
                const float bias = b0[o];
                float s = 0.0f;
                #pragma unroll
                for (int t = 0; t < 4; ++t) {
                    float v = acc[f][t][reg] + bias;
                    s += (v > 0.0f ? v : 0.0f);
                }
                s += __shfl_xor(s, 1);
                s += __shfl_xor(s, 2);
                s += __shfl_xor(s, 4);
                s += __shfl_xor(s, 8);
                if (col == 0) out[(size_t)(b0i + p) * OUTC + (o - 64)] = s;
            }
        }
    }
    __syncthreads();

    // ================= layer 1 =================
    #pragma unroll
    for (int f = 0; f < 4; ++f)
        #pragma unroll
        for (int t = 0; t < 4; ++t) acc[f][t] = (v4f)0.0f;

    {
        const _Float16* Wk = Wsw + W0_ELEMS + (size_t)(rh * 4) * 512 + (size_t)lane * 8;
        #pragma unroll 2
        for (int ks = 0; ks < 64; ++ks) {        // h = ks in [0,64), m = quad*8+j
            v8h a0 = *(const v8h*)(Wk);
            v8h a1 = *(const v8h*)(Wk + 512);
            v8h a2 = *(const v8h*)(Wk + 1024);
            v8h a3 = *(const v8h*)(Wk + 1536);
            Wk += 4096;
            #pragma unroll
            for (int t = 0; t < 4; ++t) {
                _Float16 s = h1D[p][ks * HD_PITCH + dd[t]];
                v8h s8 = {s, s, s, s, s, s, s, s};
                v8h bfr = s8 * xv8[t];
                acc[0][t] = __builtin_amdgcn_mfma_f32_16x16x32_f16(a0, bfr, acc[0][t], 0, 0, 0);
                acc[1][t] = __builtin_amdgcn_mfma_f32_16x16x32_f16(a1, bfr, acc[1][t], 0, 0, 0);
                acc[2][t] = __builtin_amdgcn_mfma_f32_16x16x32_f16(a2, bfr, acc[2][t], 0, 0, 0);
                acc[3][t] = __builtin_amdgcn_mfma_f32_16x16x32_f16(a3, bfr, acc[3][t], 0, 0, 0);
            }
        }
    }

    // ---- epilogue 1: wave's 64 rows -> out[b, 64+o] ----
    #pragma unroll
    for (int f = 0; f < 4; ++f) {
        #pragma unroll
        for (int reg = 0; reg < 4; ++reg) {
            const int o = rh * 64 + f * 16 + quad * 4 + reg;
            const float bias = b1[o];
            float s = 0.0f;
            #pragma unroll
            for (int t = 0; t < 4; ++t) {
                float v = acc[f][t][reg] + bias;
                s += (v > 0.0f ? v : 0.0f);
            }
            s += __shfl_xor(s, 1);
            s += __shfl_xor(s, 2);
            s += __shfl_xor(s, 4);
            s += __shfl_xor(s, 8);
            if (col == 0) out[(size_t)(b0i + p) * OUTC + 64 + o] = s;
        }
    }
}

extern "C" void kernel_launch(void* const* d_in, const int* in_sizes, int n_in,
                              void* d_out, int out_size, void* d_ws, size_t ws_size,
                              hipStream_t stream) {
    const float* X  = (const float*)d_in[0];
    const float* W0 = (const float*)d_in[1];
    const float* b0 = (const float*)d_in[2];
    const float* W1 = (const float*)d_in[3];
    const float* b1 = (const float*)d_in[4];
    float* out = (float*)d_out;
    _Float16* wsw = (_Float16*)d_ws;  // needs 768 KB

    convert_w_kernel<<<(CVT_THREADS + 255) / 256, 256, 0, stream>>>(W0, W1, wsw);
    cin_kernel<<<BATCH / 2, 256, 0, stream>>>(X, b0, b1, wsw, out);
}

// Round 5
// 148.706 us; speedup vs baseline: 1.2076x; 1.0097x over previous
//
#include <hip/hip_runtime.h>

// CIN forward: B=2048, F=32, DIM=64, layers (128,128)
// out[b, 0:64]   = sum_d relu(W0 @ z0 + b0)[64:128, d]
// out[b, 64:192] = sum_d relu(W1 @ z1 + b1)[0:128, d]
// z0[h*32+m, d] = x[h,d]*x[m,d]   (h,m in [0,32))
// z1[h*32+m, d] = h1[h,d]*x[m,d]  (h in [0,64), m in [0,32)), h1 = layer0 rows 0..63
//
// R5c: R5's pipelining ported onto the KNOWN-GOOD R4 shell (256 thr, 2
// batches/block, grid 1024 — the config that measured 87us; the 128-thr R5
// variants hit container failures twice, so config reverted as a hedge).
//   - explicit next-K-step a-frag rotation (aC/aN), clamped prefetch index
//     (always-valid address, dead on last iter) -> ~370cy L2 lead vs ~60cy.
//   - packed v4h B-scalar loads: xS[p][m][c*4+t] / h1S[p][h][c*4+t]; one
//     broadcast ds_read_b64 replaces 4 ds_read_u16; packed h1 ds_write_b64.
// Rationale: MfmaUtil*span == 119K cyc/CU every round -> all speedup =
// shrinking MFMA-pipe idle = un-hidden L2 latency on a-frag loads.
//
// A-frag swizzle (16x16x32): wsw[ks*4096 + s*512 + lane*8 + j]
//   = W[(s*16 + (lane&15))*K + ks*32 + (lane>>4)*8 + j]

#define BATCH 2048
#define FSZ   32
#define DIM   64
#define K0    1024
#define K1    2048
#define OUTC  192

#define W0_ELEMS (128 * K0)            // 131072 f16
#define W1_ELEMS (128 * K1)            // 262144 f16
#define TOT_ELEMS (W0_ELEMS + W1_ELEMS)
#define CVT_THREADS (TOT_ELEMS / 4)    // 98304 -> 384 blocks

typedef _Float16 v8h __attribute__((ext_vector_type(8)));
typedef _Float16 v4h __attribute__((ext_vector_type(4)));
typedef float    v4f __attribute__((ext_vector_type(4)));

#define XT_PITCH 40   // xT[d][m]: 80B rows, 16B-aligned v8h loads

// One thread per 4 output f16: coalesced 8B stores, aligned float4 reads.
__global__ void convert_w_kernel(const float* __restrict__ W0,
                                 const float* __restrict__ W1,
                                 _Float16* __restrict__ wsw) {
    int t = blockIdx.x * blockDim.x + threadIdx.x;
    if (t >= CVT_THREADS) return;
    int e = t * 4;
    const float* src;
    _Float16* dst;
    if (e < W0_ELEMS) {
        int j0 = e & 7, lane = (e >> 3) & 63, s = (e >> 9) & 7, ks = e >> 12;
        src = W0 + (size_t)(s * 16 + (lane & 15)) * K0
                 + ks * 32 + (lane >> 4) * 8 + j0;
        dst = wsw + e;
    } else {
        int u = e - W0_ELEMS;
        int j0 = u & 7, lane = (u >> 3) & 63, s = (u >> 9) & 7, ks = u >> 12;
        src = W1 + (size_t)(s * 16 + (lane & 15)) * K1
                 + ks * 32 + (lane >> 4) * 8 + j0;
        dst = wsw + W0_ELEMS + u;
    }
    float4 v = *(const float4*)src;
    dst[0] = (_Float16)v.x;
    dst[1] = (_Float16)v.y;
    dst[2] = (_Float16)v.z;
    dst[3] = (_Float16)v.w;
}

__global__ __launch_bounds__(256, 4) void cin_kernel(
    const float* __restrict__ X,      // (B, 32, 64) fp32
    const float* __restrict__ b0,     // (128,)
    const float* __restrict__ b1,     // (128,)
    const _Float16* __restrict__ Wsw, // swizzled W0 then W1 (f16)
    float* __restrict__ out)          // (B, 192) fp32
{
    __shared__ _Float16 xT[2][DIM * XT_PITCH];   // xT[p][d][m]      (10240 B)
    __shared__ _Float16 xS[2][FSZ * 64];         // xS[p][m][c*4+t]  ( 8192 B)
    __shared__ _Float16 h1S[2][64 * 64];         // h1S[p][h][c*4+t] (16384 B)

    const int b0i  = blockIdx.x * 2;
    const int tid  = threadIdx.x;
    const int wave = tid >> 6;
    const int lane = tid & 63;
    const int p    = wave & 1;        // batch member
    const int rh   = wave >> 1;       // row half (64 rows)
    const int quad = lane >> 4;
    const int col  = lane & 15;

    // ---- stage both batches' x -> LDS (both layouts, f16) ----
    #pragma unroll
    for (int i = 0; i < 4; ++i) {
        int idx = tid + i * 256;               // float4 index 0..1023
        int pp = idx >> 9, r4 = idx & 511;
        float4 v = *(const float4*)(X + (size_t)(b0i + pp) * (FSZ * DIM) + r4 * 4);
        int m = (r4 * 4) >> 6, d = (r4 * 4) & 63;
        int tq = d >> 4, c = d & 15;           // constant within the float4
        _Float16 f0 = (_Float16)v.x, f1 = (_Float16)v.y,
                 f2 = (_Float16)v.z, f3 = (_Float16)v.w;
        xT[pp][(d + 0) * XT_PITCH + m] = f0;
        xT[pp][(d + 1) * XT_PITCH + m] = f1;
        xT[pp][(d + 2) * XT_PITCH + m] = f2;
        xT[pp][(d + 3) * XT_PITCH + m] = f3;
        xS[pp][m * 64 + (c + 0) * 4 + tq] = f0;
        xS[pp][m * 64 + (c + 1) * 4 + tq] = f1;
        xS[pp][m * 64 + (c + 2) * 4 + tq] = f2;
        xS[pp][m * 64 + (c + 3) * 4 + tq] = f3;
    }
    __syncthreads();

    // K-invariant x parts of B fragments: xv8[t][j] = x[quad*8+j][16t+col]
    v8h xv8[4];
    #pragma unroll
    for (int t = 0; t < 4; ++t)
        xv8[t] = *(const v8h*)(&xT[p][(16 * t + col) * XT_PITCH + quad * 8]);

    // ================= layer 0 =================
    v4f acc[4][4];
    #pragma unroll
    for (int f = 0; f < 4; ++f)
        #pragma unroll
        for (int t = 0; t < 4; ++t) acc[f][t] = (v4f)0.0f;

    {
        const _Float16* Wb = Wsw + (size_t)(rh * 4) * 512 + (size_t)lane * 8;
        v8h aC[4], aN[4];
        v4h svC, svN;
        #pragma unroll
        for (int i = 0; i < 4; ++i) aC[i] = *(const v8h*)(Wb + i * 512);
        svC = *(const v4h*)(&xS[p][col * 4]);
        #pragma unroll 2
        for (int ks = 0; ks < 32; ++ks) {
            // clamped prefetch: last iter re-reads step 0 (valid, unused)
            const int kn = (ks + 1) & 31;
            const _Float16* Wn = Wb + (size_t)kn * 4096;
            #pragma unroll
            for (int i = 0; i < 4; ++i) aN[i] = *(const v8h*)(Wn + i * 512);
            svN = *(const v4h*)(&xS[p][kn * 64 + col * 4]);
            #pragma unroll
            for (int t = 0; t < 4; ++t) {
                _Float16 s = svC[t];
                v8h s8 = {s, s, s, s, s, s, s, s};
                v8h bfr = s8 * xv8[t];
                acc[0][t] = __builtin_amdgcn_mfma_f32_16x16x32_f16(aC[0], bfr, acc[0][t], 0, 0, 0);
                acc[1][t] = __builtin_amdgcn_mfma_f32_16x16x32_f16(aC[1], bfr, acc[1][t], 0, 0, 0);
                acc[2][t] = __builtin_amdgcn_mfma_f32_16x16x32_f16(aC[2], bfr, acc[2][t], 0, 0, 0);
                acc[3][t] = __builtin_amdgcn_mfma_f32_16x16x32_f16(aC[3], bfr, acc[3][t], 0, 0, 0);
            }
            #pragma unroll
            for (int i = 0; i < 4; ++i) aC[i] = aN[i];
            svC = svN;
        }
    }

    // ---- epilogue 0 ----
    // rh=0: rows 0..63 -> h1S[p] (packed v4h writes); rh=1: rows 64..127 -> out
    if (rh == 0) {
        #pragma unroll
        for (int f = 0; f < 4; ++f) {
            #pragma unroll
            for (int reg = 0; reg < 4; ++reg) {
                const int o = f * 16 + quad * 4 + reg;
                const float bias = b0[o];
                v4h pk;
                #pragma unroll
                for (int t = 0; t < 4; ++t) {
                    float v = acc[f][t][reg] + bias;
                    v = v > 0.0f ? v : 0.0f;
                    pk[t] = (_Float16)v;
                }
                *(v4h*)(&h1S[p][o * 64 + col * 4]) = pk;
            }
        }
    } else {
        #pragma unroll
        for (int f = 0; f < 4; ++f) {
            #pragma unroll
            for (int reg = 0; reg < 4; ++reg) {
                const int o = 64 + f * 16 + quad * 4 + reg;
                const float bias = b0[o];
                float s = 0.0f;
                #pragma unroll
                for (int t = 0; t < 4; ++t) {
                    float v = acc[f][t][reg] + bias;
                    s += (v > 0.0f ? v : 0.0f);
                }
                s += __shfl_xor(s, 1);
                s += __shfl_xor(s, 2);
                s += __shfl_xor(s, 4);
                s += __shfl_xor(s, 8);
                if (col == 0) out[(size_t)(b0i + p) * OUTC + (o - 64)] = s;
            }
        }
    }
    __syncthreads();

    // ================= layer 1 =================
    #pragma unroll
    for (int f = 0; f < 4; ++f)
        #pragma unroll
        for (int t = 0; t < 4; ++t) acc[f][t] = (v4f)0.0f;

    {
        const _Float16* Wb = Wsw + W0_ELEMS + (size_t)(rh * 4) * 512 + (size_t)lane * 8;
        v8h aC[4], aN[4];
        v4h svC, svN;
        #pragma unroll
        for (int i = 0; i < 4; ++i) aC[i] = *(const v8h*)(Wb + i * 512);
        svC = *(const v4h*)(&h1S[p][col * 4]);
        #pragma unroll 2
        for (int ks = 0; ks < 64; ++ks) {
            const int kn = (ks + 1) & 63;
            const _Float16* Wn = Wb + (size_t)kn * 4096;
            #pragma unroll
            for (int i = 0; i < 4; ++i) aN[i] = *(const v8h*)(Wn + i * 512);
            svN = *(const v4h*)(&h1S[p][kn * 64 + col * 4]);
            #pragma unroll
            for (int t = 0; t < 4; ++t) {
                _Float16 s = svC[t];
                v8h s8 = {s, s, s, s, s, s, s, s};
                v8h bfr = s8 * xv8[t];
                acc[0][t] = __builtin_amdgcn_mfma_f32_16x16x32_f16(aC[0], bfr, acc[0][t], 0, 0, 0);
                acc[1][t] = __builtin_amdgcn_mfma_f32_16x16x32_f16(aC[1], bfr, acc[1][t], 0, 0, 0);
                acc[2][t] = __builtin_amdgcn_mfma_f32_16x16x32_f16(aC[2], bfr, acc[2][t], 0, 0, 0);
                acc[3][t] = __builtin_amdgcn_mfma_f32_16x16x32_f16(aC[3], bfr, acc[3][t], 0, 0, 0);
            }
            #pragma unroll
            for (int i = 0; i < 4; ++i) aC[i] = aN[i];
            svC = svN;
        }
    }

    // ---- epilogue 1: wave's 64 rows -> out[b, 64+o] ----
    #pragma unroll
    for (int f = 0; f < 4; ++f) {
        #pragma unroll
        for (int reg = 0; reg < 4; ++reg) {
            const int o = rh * 64 + f * 16 + quad * 4 + reg;
            const float bias = b1[o];
            float s = 0.0f;
            #pragma unroll
            for (int t = 0; t < 4; ++t) {
                float v = acc[f][t][reg] + bias;
                s += (v > 0.0f ? v : 0.0f);
            }
            s += __shfl_xor(s, 1);
            s += __shfl_xor(s, 2);
            s += __shfl_xor(s, 4);
            s += __shfl_xor(s, 8);
            if (col == 0) out[(size_t)(b0i + p) * OUTC + 64 + o] = s;
        }
    }
}

extern "C" void kernel_launch(void* const* d_in, const int* in_sizes, int n_in,
                              void* d_out, int out_size, void* d_ws, size_t ws_size,
                              hipStream_t stream) {
    const float* X  = (const float*)d_in[0];
    const float* W0 = (const float*)d_in[1];
    const float* b0 = (const float*)d_in[2];
    const float* W1 = (const float*)d_in[3];
    const float* b1 = (const float*)d_in[4];
    float* out = (float*)d_out;
    _Float16* wsw = (_Float16*)d_ws;  // needs 768 KB

    convert_w_kernel<<<(CVT_THREADS + 255) / 256, 256, 0, stream>>>(W0, W1, wsw);
    cin_kernel<<<BATCH / 2, 256, 0, stream>>>(X, b0, b1, wsw, out);
}

// Round 6
// 147.095 us; speedup vs baseline: 1.2208x; 1.0110x over previous
//
#include <hip/hip_runtime.h>

// CIN forward: B=2048, F=32, DIM=64, layers (128,128)
// out[b, 0:64]   = sum_d relu(W0 @ z0 + b0)[64:128, d]
// out[b, 64:192] = sum_d relu(W1 @ z1 + b1)[0:128, d]
// z0[h*32+m, d] = x[h,d]*x[m,d]   (h,m in [0,32))
// z1[h*32+m, d] = h1[h,d]*x[m,d]  (h in [0,64), m in [0,32)), h1 = layer0 rows 0..63
//
// R6: 4 batches/block (512 thr, 8 waves = (p 0..3, rh 0..1)) with W staged
// through LDS via global_load_lds double-buffer (T3 minimum 2-phase recipe):
//   - R5c showed 370cy prefetch lead bought only +3% -> stall is not simple
//     load latency; it's duplicated W vector-load traffic (p-paired waves
//     loading identical frags) + L2 contention + rotation VALU overhead.
//   - One 8KB stage per block per K-step serves 4 batches (4x less W request
//     traffic per batch); frags come from conflict-free ds_read_b128; no
//     rotation movs, no per-iter global addressing.
//   - h1S overlays xT+xS (dead after layer-0 K-loop): LDS 53.2KB -> 2 blk/CU.
//   - last L0 iter prefetches L1 tile 0 (uniform select) across the barrier.
//
// A-frag swizzle (16x16x32): wsw[ks*4096 + s*512 + lane*8 + j]
//   = W[(s*16 + (lane&15))*K + ks*32 + (lane>>4)*8 + j]
// K-step tile = 4096 elems (8 streams x 512) = 8KB, contiguous in wsw.

#define BATCH 2048
#define FSZ   32
#define DIM   64
#define K0    1024
#define K1    2048
#define OUTC  192

#define W0_ELEMS (128 * K0)            // 131072 f16
#define W1_ELEMS (128 * K1)            // 262144 f16
#define TOT_ELEMS (W0_ELEMS + W1_ELEMS)
#define CVT_THREADS (TOT_ELEMS / 4)    // 98304 -> 384 blocks

typedef _Float16 v8h __attribute__((ext_vector_type(8)));
typedef _Float16 v4h __attribute__((ext_vector_type(4)));
typedef float    v4f __attribute__((ext_vector_type(4)));

#define XT_PITCH 40   // xT[d][m]: 80B rows, 16B-aligned v8h loads

// One thread per 4 output f16: coalesced 8B stores, aligned float4 reads.
__global__ void convert_w_kernel(const float* __restrict__ W0,
                                 const float* __restrict__ W1,
                                 _Float16* __restrict__ wsw) {
    int t = blockIdx.x * blockDim.x + threadIdx.x;
    if (t >= CVT_THREADS) return;
    int e = t * 4;
    const float* src;
    _Float16* dst;
    if (e < W0_ELEMS) {
        int j0 = e & 7, lane = (e >> 3) & 63, s = (e >> 9) & 7, ks = e >> 12;
        src = W0 + (size_t)(s * 16 + (lane & 15)) * K0
                 + ks * 32 + (lane >> 4) * 8 + j0;
        dst = wsw + e;
    } else {
        int u = e - W0_ELEMS;
        int j0 = u & 7, lane = (u >> 3) & 63, s = (u >> 9) & 7, ks = u >> 12;
        src = W1 + (size_t)(s * 16 + (lane & 15)) * K1
                 + ks * 32 + (lane >> 4) * 8 + j0;
        dst = wsw + W0_ELEMS + u;
    }
    float4 v = *(const float4*)src;
    dst[0] = (_Float16)v.x;
    dst[1] = (_Float16)v.y;
    dst[2] = (_Float16)v.z;
    dst[3] = (_Float16)v.w;
}

// Wave-cooperative stage of 1KB: per-lane global src, wave-uniform LDS dest
// (HW adds lane*16 to the LDS base).
__device__ __forceinline__ void stage_w(const _Float16* gsrc, _Float16* ldst) {
    __builtin_amdgcn_global_load_lds(
        (const __attribute__((address_space(1))) void*)gsrc,
        (__attribute__((address_space(3))) void*)ldst,
        16, 0, 0);
}

__global__ __launch_bounds__(512, 4) void cin_kernel(
    const float* __restrict__ X,      // (B, 32, 64) fp32
    const float* __restrict__ b0,     // (128,)
    const float* __restrict__ b1,     // (128,)
    const _Float16* __restrict__ Wsw, // swizzled W0 then W1 (f16)
    float* __restrict__ out)          // (B, 192) fp32
{
    __shared__ _Float16 wbuf[2][4096];  // 16 KB W double-buffer (8KB tiles)
    __shared__ _Float16 xmem[18432];    // 36 KB: xT[4]+xS[4], overlaid by h1S[4]

    _Float16* const xT  = xmem;           // xT[p]  at p*2560: [64][40]
    _Float16* const xS  = xmem + 10240;   // xS[p]  at p*2048: [32][64]
    _Float16* const h1S = xmem;           // h1S[p] at p*4096: [64][64] (overlay)

    const int tid  = threadIdx.x;
    const int wave = tid >> 6;
    const int lane = tid & 63;
    const int p    = wave & 3;        // batch member 0..3
    const int rh   = wave >> 2;       // row half (64 rows)
    const int quad = lane >> 4;
    const int col  = lane & 15;
    const int b0i  = blockIdx.x * 4;

    // ---- stage 4 batches' x -> LDS (both layouts, f16) ----
    #pragma unroll
    for (int i = 0; i < 4; ++i) {
        int idx = tid + i * 512;               // float4 index 0..2047
        int pp = idx >> 9, r4 = idx & 511;
        float4 v = *(const float4*)(X + (size_t)(b0i + pp) * (FSZ * DIM) + r4 * 4);
        int m = (r4 * 4) >> 6, d = (r4 * 4) & 63;
        int tq = d >> 4, cc = d & 15;          // constant within the float4
        _Float16 f0 = (_Float16)v.x, f1 = (_Float16)v.y,
                 f2 = (_Float16)v.z, f3 = (_Float16)v.w;
        _Float16* xTp = xT + pp * 2560;
        _Float16* xSp = xS + pp * 2048;
        xTp[(d + 0) * XT_PITCH + m] = f0;
        xTp[(d + 1) * XT_PITCH + m] = f1;
        xTp[(d + 2) * XT_PITCH + m] = f2;
        xTp[(d + 3) * XT_PITCH + m] = f3;
        xSp[m * 64 + (cc + 0) * 4 + tq] = f0;
        xSp[m * 64 + (cc + 1) * 4 + tq] = f1;
        xSp[m * 64 + (cc + 2) * 4 + tq] = f2;
        xSp[m * 64 + (cc + 3) * 4 + tq] = f3;
    }
    // stage W tile 0 (layer 0) concurrently with x staging; barrier drains it
    stage_w(Wsw + (size_t)wave * 512 + lane * 8, &wbuf[0][wave * 512]);
    __syncthreads();

    // K-invariant x parts of B fragments: xv8[t][j] = x[quad*8+j][16t+col]
    v8h xv8[4];
    #pragma unroll
    for (int t = 0; t < 4; ++t)
        xv8[t] = *(const v8h*)(xT + p * 2560 + (16 * t + col) * XT_PITCH + quad * 8);

    // ================= layer 0 =================
    v4f acc[4][4];
    #pragma unroll
    for (int f = 0; f < 4; ++f)
        #pragma unroll
        for (int t = 0; t < 4; ++t) acc[f][t] = (v4f)0.0f;

    const int fragOff = rh * 2048 + lane * 8;  // this wave's frag base in a wbuf
    int c = 0;
    for (int ks = 0; ks < 32; ++ks) {
        // prefetch next tile; on last iter prefetch layer-1 tile 0
        const size_t nxt = (ks < 31) ? (size_t)(ks + 1) * 4096 : (size_t)W0_ELEMS;
        stage_w(Wsw + nxt + wave * 512 + lane * 8, &wbuf[c ^ 1][wave * 512]);

        v4h sv = *(const v4h*)(xS + p * 2048 + ks * 64 + col * 4);
        const _Float16* wb = &wbuf[c][fragOff];
        v8h a0 = *(const v8h*)(wb);
        v8h a1 = *(const v8h*)(wb + 512);
        v8h a2 = *(const v8h*)(wb + 1024);
        v8h a3 = *(const v8h*)(wb + 1536);
        #pragma unroll
        for (int t = 0; t < 4; ++t) {
            _Float16 s = sv[t];
            v8h s8 = {s, s, s, s, s, s, s, s};
            v8h bfr = s8 * xv8[t];
            acc[0][t] = __builtin_amdgcn_mfma_f32_16x16x32_f16(a0, bfr, acc[0][t], 0, 0, 0);
            acc[1][t] = __builtin_amdgcn_mfma_f32_16x16x32_f16(a1, bfr, acc[1][t], 0, 0, 0);
            acc[2][t] = __builtin_amdgcn_mfma_f32_16x16x32_f16(a2, bfr, acc[2][t], 0, 0, 0);
            acc[3][t] = __builtin_amdgcn_mfma_f32_16x16x32_f16(a3, bfr, acc[3][t], 0, 0, 0);
        }
        __syncthreads();   // staged tile landed (vmcnt drain) + reads of wbuf[c] done
        c ^= 1;
    }
    // after loop: c == 0, layer-1 tile 0 already sits in wbuf[0]

    // ---- epilogue 0 ----
    // rh=0: rows 0..63 -> h1S[p] (overlay; xT/xS dead); rh=1: rows 64..127 -> out
    if (rh == 0) {
        #pragma unroll
        for (int f = 0; f < 4; ++f) {
            #pragma unroll
            for (int reg = 0; reg < 4; ++reg) {
                const int o = f * 16 + quad * 4 + reg;
                const float bias = b0[o];
                v4h pk;
                #pragma unroll
                for (int t = 0; t < 4; ++t) {
                    float v = acc[f][t][reg] + bias;
                    v = v > 0.0f ? v : 0.0f;
                    pk[t] = (_Float16)v;
                }
                *(v4h*)(h1S + p * 4096 + o * 64 + col * 4) = pk;
            }
        }
    } else {
        #pragma unroll
        for (int f = 0; f < 4; ++f) {
            #pragma unroll
            for (int reg = 0; reg < 4; ++reg) {
                const int o = 64 + f * 16 + quad * 4 + reg;
                const float bias = b0[o];
                float s = 0.0f;
                #pragma unroll
                for (int t = 0; t < 4; ++t) {
                    float v = acc[f][t][reg] + bias;
                    s += (v > 0.0f ? v : 0.0f);
                }
                s += __shfl_xor(s, 1);
                s += __shfl_xor(s, 2);
                s += __shfl_xor(s, 4);
                s += __shfl_xor(s, 8);
                if (col == 0) out[(size_t)(b0i + p) * OUTC + (o - 64)] = s;
            }
        }
    }
    __syncthreads();   // h1S visible to all waves

    // ================= layer 1 =================
    #pragma unroll
    for (int f = 0; f < 4; ++f)
        #pragma unroll
        for (int t = 0; t < 4; ++t) acc[f][t] = (v4f)0.0f;

    for (int ks = 0; ks < 64; ++ks) {
        if (ks < 63)
            stage_w(Wsw + (size_t)W0_ELEMS + (size_t)(ks + 1) * 4096 + wave * 512 + lane * 8,
                    &wbuf[c ^ 1][wave * 512]);

        v4h sv = *(const v4h*)(h1S + p * 4096 + ks * 64 + col * 4);
        const _Float16* wb = &wbuf[c][fragOff];
        v8h a0 = *(const v8h*)(wb);
        v8h a1 = *(const v8h*)(wb + 512);
        v8h a2 = *(const v8h*)(wb + 1024);
        v8h a3 = *(const v8h*)(wb + 1536);
        #pragma unroll
        for (int t = 0; t < 4; ++t) {
            _Float16 s = sv[t];
            v8h s8 = {s, s, s, s, s, s, s, s};
            v8h bfr = s8 * xv8[t];
            acc[0][t] = __builtin_amdgcn_mfma_f32_16x16x32_f16(a0, bfr, acc[0][t], 0, 0, 0);
            acc[1][t] = __builtin_amdgcn_mfma_f32_16x16x32_f16(a1, bfr, acc[1][t], 0, 0, 0);
            acc[2][t] = __builtin_amdgcn_mfma_f32_16x16x32_f16(a2, bfr, acc[2][t], 0, 0, 0);
            acc[3][t] = __builtin_amdgcn_mfma_f32_16x16x32_f16(a3, bfr, acc[3][t], 0, 0, 0);
        }
        __syncthreads();
        c ^= 1;
    }

    // ---- epilogue 1: wave's 64 rows -> out[b, 64+o] ----
    #pragma unroll
    for (int f = 0; f < 4; ++f) {
        #pragma unroll
        for (int reg = 0; reg < 4; ++reg) {
            const int o = rh * 64 + f * 16 + quad * 4 + reg;
            const float bias = b1[o];
            float s = 0.0f;
            #pragma unroll
            for (int t = 0; t < 4; ++t) {
                float v = acc[f][t][reg] + bias;
                s += (v > 0.0f ? v : 0.0f);
            }
            s += __shfl_xor(s, 1);
            s += __shfl_xor(s, 2);
            s += __shfl_xor(s, 4);
            s += __shfl_xor(s, 8);
            if (col == 0) out[(size_t)(b0i + p) * OUTC + 64 + o] = s;
        }
    }
}

extern "C" void kernel_launch(void* const* d_in, const int* in_sizes, int n_in,
                              void* d_out, int out_size, void* d_ws, size_t ws_size,
                              hipStream_t stream) {
    const float* X  = (const float*)d_in[0];
    const float* W0 = (const float*)d_in[1];
    const float* b0 = (const float*)d_in[2];
    const float* W1 = (const float*)d_in[3];
    const float* b1 = (const float*)d_in[4];
    float* out = (float*)d_out;
    _Float16* wsw = (_Float16*)d_ws;  // needs 768 KB

    convert_w_kernel<<<(CVT_THREADS + 255) / 256, 256, 0, stream>>>(W0, W1, wsw);
    cin_kernel<<<BATCH / 4, 512, 0, stream>>>(X, b0, b1, wsw, out);
}